// Round 7
// baseline (322.286 us; speedup 1.0000x reference)
//
#include <hip/hip_runtime.h>
#include <hip/hip_bf16.h>

typedef unsigned short u16;
typedef unsigned int u32;
typedef __attribute__((ext_vector_type(8))) short bf16x8;
typedef __attribute__((ext_vector_type(4))) float f32x4;

#define MFMA16(a, b, c) __builtin_amdgcn_mfma_f32_16x16x32_bf16(a, b, c, 0, 0, 0)

// fold of softmax scale into Q projection: exp(s/8) = 2^(s*0.125*log2(e))
#define QSCALE 0.18033688011112042f

__device__ inline u16 f2b(float f) {
    union { float f; unsigned int i; } v;
    v.f = f;
    unsigned int r = v.i + 0x7fffu + ((v.i >> 16) & 1u);
    return (u16)(r >> 16);
}
__device__ inline u32 fbits(float f) {
    union { float f; u32 i; } v; v.f = f; return v.i;
}
// pack two fp32 -> [bf16(f0) | bf16(f1)<<16], truncation, 1 v_perm_b32
__device__ inline u32 pack2_trunc(float f0, float f1) {
    return __builtin_amdgcn_perm(fbits(f1), fbits(f0), 0x07060302u);
}

// async global->LDS, 16B per lane (wave-uniform base + lane*16 dest).
__device__ inline void glds16(const u16* g, u16* l) {
    __builtin_amdgcn_global_load_lds(
        (const __attribute__((address_space(1))) unsigned int*)g,
        (__attribute__((address_space(3))) unsigned int*)l, 16, 0, 0);
}

// All six fp32->bf16 conversions in ONE dispatch, flat 1D decode.
// chunks: query 4096 | value 4096 | wq/wk/wv/wo 512 each  (total 10240)
__global__ __launch_bounds__(256) void cvt_all(
    const float* __restrict__ q, const float* __restrict__ v,
    const float* __restrict__ wq, const float* __restrict__ wk,
    const float* __restrict__ wv, const float* __restrict__ wo,
    u16* __restrict__ qb, u16* __restrict__ vb,
    u16* __restrict__ wqb, u16* __restrict__ wkb,
    u16* __restrict__ wvb, u16* __restrict__ wob)
{
    int flat = blockIdx.x;
    const float* x; u16* y; int off;
    if (flat < 8192) {
        x = flat < 4096 ? q : v;
        y = flat < 4096 ? qb : vb;
        off = flat & 4095;
    } else {
        int s = (flat - 8192) >> 9;
        off = (flat - 8192) & 511;
        x = s == 0 ? wq : (s == 1 ? wk : (s == 2 ? wv : wo));
        y = s == 0 ? wqb : (s == 1 ? wkb : (s == 2 ? wvb : wob));
    }
    int i = (off * 256 + threadIdx.x) * 8;
    float4 a = *(const float4*)(x + i);
    float4 b = *(const float4*)(x + i + 4);
    u16 o[8] = { f2b(a.x), f2b(a.y), f2b(a.z), f2b(a.w),
                 f2b(b.x), f2b(b.y), f2b(b.z), f2b(b.w) };
    *(uint4*)(y + i) = *(uint4*)o;
}

// Fused Q/K/V projections, BM=256 x BN=128, BK=32 (m97-style 2-barrier loop).
// BM=256 halves W staging traffic vs BM=128 (R4: L2/L3-BW-bound on staging).
// acc[8][4]=128 VGPR -> ~190 live, 2 waves/SIMD; launch_bounds(256,2) allows
// 256 VGPR (no spill). Grid 768 = 8 xcd x 4 m x 24 y (XCD-clustered).
// sel==2 (V) writes its output DIRECTLY TRANSPOSED into VT[(b*1024+d)*2048+l].
__global__ __launch_bounds__(256, 2) void gemm_proj(
    const u16* __restrict__ qb, const u16* __restrict__ vb,
    const u16* __restrict__ wqb, const u16* __restrict__ wkb,
    const u16* __restrict__ wvb,
    const float* __restrict__ bq, const float* __restrict__ bk,
    const float* __restrict__ bv,
    u16* __restrict__ Qp, u16* __restrict__ Kp, u16* __restrict__ VT,
    int M, int K)
{
    const int flat = blockIdx.x;
    const int xcd = flat & 7, idx = flat >> 3;     // idx in 0..95
    const int mt  = xcd * 4 + (idx & 3);           // m-tile 0..31 (256 rows each)
    const int yy  = idx >> 2;                      // 0..23
    const int sel = yy >> 3;
    const int n0 = (yy & 7) * 128;
    const u16* A = sel ? vb : qb;
    const u16* W = sel == 0 ? wqb : (sel == 1 ? wkb : wvb);
    const float* bias = sel == 0 ? bq : (sel == 1 ? bk : bv);
    const float cscale = sel == 0 ? QSCALE : 1.0f;

    __shared__ __align__(16) u16 As[256 * 32];     // 16 KB
    __shared__ __align__(16) u16 Bs[128 * 32];     //  8 KB

    const int tid  = threadIdx.x;
    const int wave = tid >> 6, lane = tid & 63;
    const int quad = lane >> 4, l16 = lane & 15;
    const int m0 = mt * 256;
    const int wm = (wave >> 1) * 128, wn = (wave & 1) * 64;
    const int r0 = lane >> 2;
    const int c0 = (lane & 3) * 8;

    f32x4 acc[8][4] = {};

    for (int k0 = 0; k0 < K; k0 += 32) {
        __syncthreads();
        {
            int ra = wave * 16 + r0;
#pragma unroll
            for (int s = 0; s < 4; ++s)
                glds16(&A[(size_t)(m0 + s * 64 + ra) * K + k0 + c0],
                       &As[(s * 64 + ra) * 32 + c0]);
#pragma unroll
            for (int s = 0; s < 2; ++s)
                glds16(&W[(size_t)(n0 + s * 64 + ra) * K + k0 + c0],
                       &Bs[(s * 64 + ra) * 32 + c0]);
        }
        __syncthreads();

        bf16x8 af[8], bfr[4];
#pragma unroll
        for (int mi = 0; mi < 8; ++mi)
            af[mi] = *(const bf16x8*)(&As[(wm + mi * 16 + l16) * 32 + quad * 8]);
#pragma unroll
        for (int ni = 0; ni < 4; ++ni)
            bfr[ni] = *(const bf16x8*)(&Bs[(wn + ni * 16 + l16) * 32 + quad * 8]);
#pragma unroll
        for (int mi = 0; mi < 8; ++mi)
#pragma unroll
            for (int ni = 0; ni < 4; ++ni)
                acc[mi][ni] = MFMA16(af[mi], bfr[ni], acc[mi][ni]);
    }

    if (sel == 2) {
        // transposed V epilogue: VT[(b*1024+col)*2048 + l], l = row & 2047
#pragma unroll
        for (int mi = 0; mi < 8; ++mi) {
#pragma unroll
            for (int ni = 0; ni < 4; ++ni) {
                int col = n0 + wn + ni * 16 + l16;
                float bv2 = bias[col];
                int row0 = m0 + wm + mi * 16 + quad * 4;   // + r, r=0..3
                int bb = row0 >> 11, l0 = row0 & 2047;
                u16 o[4];
#pragma unroll
                for (int r = 0; r < 4; ++r) o[r] = f2b(acc[mi][ni][r] + bv2);
                *(uint2*)(&VT[((size_t)bb * 1024 + col) * 2048 + l0]) = *(uint2*)o;
            }
        }
    } else {
        u16* C = sel == 0 ? Qp : Kp;
#pragma unroll
        for (int mi = 0; mi < 8; ++mi) {
#pragma unroll
            for (int ni = 0; ni < 4; ++ni) {
                int col = n0 + wn + ni * 16 + l16;
                float bv2 = bias[col];
#pragma unroll
                for (int r = 0; r < 4; ++r) {
                    int row = m0 + wm + mi * 16 + quad * 4 + r;
                    C[(size_t)row * 1024 + col] = f2b((acc[mi][ni][r] + bv2) * cscale);
                }
            }
        }
    }
}

// Output GEMM: C[M,N](fp32) = A[M,K](bf16) @ B[N,K]^T(bf16) + bias.
// m97 structure; XCD-clustered 1D grid (512 = 8 xcd x 8 m x 8 n).
__global__ __launch_bounds__(256) void gemm_out(
    const u16* __restrict__ A, const u16* __restrict__ B,
    const float* __restrict__ bias, float* __restrict__ C,
    int M, int N, int K)
{
    __shared__ __align__(16) u16 As[128 * 32];
    __shared__ __align__(16) u16 Bs[128 * 32];

    const int flat = blockIdx.x;
    const int xcd = flat & 7, idx = flat >> 3;     // idx 0..63
    const int mt  = xcd * 8 + (idx & 7);
    const int m0 = mt * 128, n0 = (idx >> 3) * 128;

    const int tid  = threadIdx.x;
    const int wave = tid >> 6, lane = tid & 63;
    const int quad = lane >> 4, l16 = lane & 15;
    const int wm = (wave >> 1) * 64, wn = (wave & 1) * 64;
    const int r0 = lane >> 2;
    const int c0 = (lane & 3) * 8;

    f32x4 acc[4][4] = {};

    for (int k0 = 0; k0 < K; k0 += 32) {
        __syncthreads();
        {
            int ra = wave * 16 + r0;
            glds16(&A[(size_t)(m0 + ra) * K + k0 + c0],      &As[ra * 32 + c0]);
            glds16(&A[(size_t)(m0 + 64 + ra) * K + k0 + c0], &As[(64 + ra) * 32 + c0]);
            glds16(&B[(size_t)(n0 + ra) * K + k0 + c0],      &Bs[ra * 32 + c0]);
            glds16(&B[(size_t)(n0 + 64 + ra) * K + k0 + c0], &Bs[(64 + ra) * 32 + c0]);
        }
        __syncthreads();

        bf16x8 af[4], bfr[4];
#pragma unroll
        for (int mi = 0; mi < 4; ++mi)
            af[mi] = *(const bf16x8*)(&As[(wm + mi * 16 + l16) * 32 + quad * 8]);
#pragma unroll
        for (int ni = 0; ni < 4; ++ni)
            bfr[ni] = *(const bf16x8*)(&Bs[(wn + ni * 16 + l16) * 32 + quad * 8]);
#pragma unroll
        for (int mi = 0; mi < 4; ++mi)
#pragma unroll
            for (int ni = 0; ni < 4; ++ni)
                acc[mi][ni] = MFMA16(af[mi], bfr[ni], acc[mi][ni]);
    }

#pragma unroll
    for (int mi = 0; mi < 4; ++mi) {
#pragma unroll
        for (int ni = 0; ni < 4; ++ni) {
            int col = n0 + wn + ni * 16 + l16;
            float bv = bias[col];
#pragma unroll
            for (int r = 0; r < 4; ++r) {
                int row = m0 + wm + mi * 16 + quad * 4 + r;
                C[(size_t)row * N + col] = acc[mi][ni][r] + bv;
            }
        }
    }
}

// Flash attention, 2 waves x 64 q-rows, V read DIRECT from L2 (no V-staging).
// R6 analysis: attn LDS-pipe-bound (~51 of 90 us). V-tile is L2-resident
// (per-XCD KV set ~4 MB, FETCH confirms single HBM fetch) and the vf read
// pattern is layout-identical global vs LDS (16B/lane, 64B/quad contiguous)
// -> guide Common-mistake #7 (m169): stage only K, load vf straight from VT.
// Saves vf-LDS-reads + V-staging-writes (~30% of LDS cycles); LDS 28->19 KB.
// vf loads for both ks issued right after QK^T; ~300cy of exp2/pack/DS work
// hides L2 latency. Peak regs ~230 < 256 cap (launch_bounds(128,2));
// WRITE_SIZE is the spill tattletale (R2 lesson).
// Q pre-scaled by 0.125*log2e so p = exp2(S), max-free. S computed
// TRANSPOSED (mfma(kf,qf)); pack 4 truncated bf16 -> one ds_write_b64;
// denominator via vones MFMA = exactly consistent with truncated P.
__global__ __launch_bounds__(128, 2) void attn(
    const u16* __restrict__ Q, const u16* __restrict__ K,
    const u16* __restrict__ VT, u16* __restrict__ O,
    int LQ, int LK)
{
    const int tid  = threadIdx.x;
    const int wave = tid >> 6, lane = tid & 63;
    const int quad = lane >> 4, l16 = lane & 15;
    // XCD-clustered decode (bijective, 8 xcd x 8 bh x 16 q-blocks = 1024):
    const int flat = blockIdx.x;
    const int xcd = flat & 7, slot = flat >> 3;
    const int bh = xcd * 8 + (slot >> 4);
    const int q0 = (slot & 15) * 128;
    const int b = bh >> 4, h = bh & 15;
    const size_t qbase = ((size_t)b * LQ + q0) * 1024 + h * 64;
    const size_t kbase = ((size_t)b * LK) * 1024 + h * 64;
    const size_t vtbase = ((size_t)b * 1024 + h * 64) * 2048;

    __shared__ __align__(16) u16 Ks[64 * 72];        // [krow][d]   9 KB
    __shared__ __align__(16) u16 Ps[2][64 * 40];     // per-wave P ks-slice 10 KB

    bf16x8 qf[4][2];
#pragma unroll
    for (int mi = 0; mi < 4; ++mi)
#pragma unroll
        for (int ks = 0; ks < 2; ++ks)
            qf[mi][ks] = *(const bf16x8*)(
                &Q[qbase + (size_t)(wave * 64 + mi * 16 + l16) * 1024 + ks * 32 + quad * 8]);

    const bf16x8 vones = { 0x3F80, 0x3F80, 0x3F80, 0x3F80,
                           0x3F80, 0x3F80, 0x3F80, 0x3F80 };

    f32x4 oacc[4][5] = {};   // [q-tile][4 d-tiles + 1 rowsum tile]

    for (int kt = 0; kt < LK; kt += 64) {
        __syncthreads();               // WAR: prior iter's kf reads done
#pragma unroll
        for (int i = 0; i < 4; ++i) {
            int ch = tid + i * 128;
            int row = ch >> 3, c8 = (ch & 7) * 8;
            *(uint4*)(&Ks[row * 72 + c8]) =
                *(const uint4*)(&K[kbase + (size_t)(kt + row) * 1024 + c8]);
        }
        __syncthreads();               // K tile published

        // S^T tiles: st[ni][mi] = K-tile(ni) x Q-tile(mi); lane (quad,l16) reg r
        // holds S[q = mi*16+l16][k = ni*16+quad*4+r]
        f32x4 st[4][4] = {};
#pragma unroll
        for (int ks = 0; ks < 2; ++ks) {
            bf16x8 kf[4];
#pragma unroll
            for (int ni = 0; ni < 4; ++ni)
                kf[ni] = *(const bf16x8*)(&Ks[(ni * 16 + l16) * 72 + ks * 32 + quad * 8]);
            __builtin_amdgcn_s_setprio(1);
#pragma unroll
            for (int ni = 0; ni < 4; ++ni)
#pragma unroll
                for (int mi = 0; mi < 4; ++mi)
                    st[ni][mi] = MFMA16(kf[ni], qf[mi][ks], st[ni][mi]);
            __builtin_amdgcn_s_setprio(0);
        }

        // V fragments DIRECT from global (L2-resident); issued here so the
        // exp2/pack/Ps phase below covers the latency.
        bf16x8 vf2[2][4];
#pragma unroll
        for (int ks = 0; ks < 2; ++ks)
#pragma unroll
            for (int nd = 0; nd < 4; ++nd)
                vf2[ks][nd] = *(const bf16x8*)(
                    &VT[vtbase + (size_t)(nd * 16 + l16) * 2048 + kt + ks * 32 + quad * 8]);

        // per 32-col ks-slice: p = exp2(s), pack -> Ps slice, then PV MFMA.
        // Ps is wave-private; same-wave in-order DS ops give RAW/WAR ordering.
#pragma unroll
        for (int ks = 0; ks < 2; ++ks) {
#pragma unroll
            for (int mi = 0; mi < 4; ++mi)
#pragma unroll
                for (int ni2 = 0; ni2 < 2; ++ni2) {
                    const f32x4 s4 = st[ks * 2 + ni2][mi];
                    float p0 = __builtin_amdgcn_exp2f(s4[0]);
                    float p1 = __builtin_amdgcn_exp2f(s4[1]);
                    float p2 = __builtin_amdgcn_exp2f(s4[2]);
                    float p3 = __builtin_amdgcn_exp2f(s4[3]);
                    uint2 w;
                    w.x = pack2_trunc(p0, p1);
                    w.y = pack2_trunc(p2, p3);
                    *(uint2*)(&Ps[wave][(mi * 16 + l16) * 40 + ni2 * 16 + quad * 4]) = w;
                }

            __builtin_amdgcn_s_setprio(1);
#pragma unroll
            for (int mi = 0; mi < 4; ++mi) {
                bf16x8 pf = *(const bf16x8*)(&Ps[wave][(mi * 16 + l16) * 40 + quad * 8]);
#pragma unroll
                for (int nd = 0; nd < 4; ++nd)
                    oacc[mi][nd] = MFMA16(pf, vf2[ks][nd], oacc[mi][nd]);
                oacc[mi][4] = MFMA16(pf, vones, oacc[mi][4]);
            }
            __builtin_amdgcn_s_setprio(0);
        }
    }

    // epilogue: divide by MFMA-computed row sums, store
#pragma unroll
    for (int mi = 0; mi < 4; ++mi)
#pragma unroll
        for (int r = 0; r < 4; ++r) {
            float inv = 1.0f / oacc[mi][4][r];
            int row = q0 + wave * 64 + mi * 16 + quad * 4 + r;
            size_t rb = ((size_t)b * LQ + row) * 1024 + h * 64;
#pragma unroll
            for (int nd = 0; nd < 4; ++nd)
                O[rb + nd * 16 + l16] = f2b(oacc[mi][nd][r] * inv);
        }
}

extern "C" void kernel_launch(void* const* d_in, const int* in_sizes, int n_in,
                              void* d_out, int out_size, void* d_ws, size_t ws_size,
                              hipStream_t stream) {
    const float* query = (const float*)d_in[0];
    const float* value = (const float*)d_in[1];
    const float* wq = (const float*)d_in[2];
    const float* bq = (const float*)d_in[3];
    const float* wk = (const float*)d_in[4];
    const float* bk = (const float*)d_in[5];
    const float* wv = (const float*)d_in[6];
    const float* bv = (const float*)d_in[7];
    const float* wo = (const float*)d_in[8];
    const float* bo = (const float*)d_in[9];

    const int B = 4, LQ = 2048, LK = 2048, D = 1024;
    const int M = B * LQ;                 // 8192
    const int mat = M * D;                // 8388608
    const int wsz = D * D;                // 1048576

    // ws (u16): qb vb | wqb wkb wvb wob | Qp Kp Cp VT  = 104 MB
    u16* ws  = (u16*)d_ws;
    u16* qb  = ws;
    u16* vb  = qb + mat;
    u16* wqb = vb + mat;
    u16* wkb = wqb + wsz;
    u16* wvb = wkb + wsz;
    u16* wob = wvb + wsz;
    u16* Qp  = wob + wsz;
    u16* Kp  = Qp + mat;
    u16* Cp  = Kp + mat;                  // attn output
    u16* VT  = Cp + mat;                  // V projection, stored transposed

    dim3 blk(256);

    cvt_all<<<dim3(10240), blk, 0, stream>>>(
        query, value, wq, wk, wv, wo, qb, vb, wqb, wkb, wvb, wob);

    // fused Q/K/V projections: BM=256, XCD-clustered flat grid (768 blocks);
    // V written directly transposed into VT.
    gemm_proj<<<dim3(768), blk, 0, stream>>>(
        qb, vb, wqb, wkb, wvb, bq, bk, bv, Qp, Kp, VT, M, D);

    attn<<<dim3(1024), dim3(128), 0, stream>>>(Qp, Kp, VT, Cp, LQ, LK);

    gemm_out<<<dim3(512), blk, 0, stream>>>(Cp, wob, bo, (float*)d_out, M, D, D);
}

// Round 8
// 316.079 us; speedup vs baseline: 1.0196x; 1.0196x over previous
//
#include <hip/hip_runtime.h>
#include <hip/hip_bf16.h>

typedef unsigned short u16;
typedef unsigned int u32;
typedef __attribute__((ext_vector_type(8))) short bf16x8;
typedef __attribute__((ext_vector_type(4))) float f32x4;

#define MFMA16(a, b, c) __builtin_amdgcn_mfma_f32_16x16x32_bf16(a, b, c, 0, 0, 0)

// fold of softmax scale into Q projection: exp(s/8) = 2^(s*0.125*log2(e))
#define QSCALE 0.18033688011112042f

__device__ inline u16 f2b(float f) {
    union { float f; unsigned int i; } v;
    v.f = f;
    unsigned int r = v.i + 0x7fffu + ((v.i >> 16) & 1u);
    return (u16)(r >> 16);
}
__device__ inline u32 fbits(float f) {
    union { float f; u32 i; } v; v.f = f; return v.i;
}
// pack two fp32 -> [bf16(f0) | bf16(f1)<<16], truncation, 1 v_perm_b32
__device__ inline u32 pack2_trunc(float f0, float f1) {
    return __builtin_amdgcn_perm(fbits(f1), fbits(f0), 0x07060302u);
}

// async global->LDS, 16B per lane (wave-uniform base + lane*16 dest).
__device__ inline void glds16(const u16* g, u16* l) {
    __builtin_amdgcn_global_load_lds(
        (const __attribute__((address_space(1))) unsigned int*)g,
        (__attribute__((address_space(3))) unsigned int*)l, 16, 0, 0);
}

// All six fp32->bf16 conversions in ONE dispatch, flat 1D decode.
// chunks: query 4096 | value 4096 | wq/wk/wv/wo 512 each  (total 10240)
__global__ __launch_bounds__(256) void cvt_all(
    const float* __restrict__ q, const float* __restrict__ v,
    const float* __restrict__ wq, const float* __restrict__ wk,
    const float* __restrict__ wv, const float* __restrict__ wo,
    u16* __restrict__ qb, u16* __restrict__ vb,
    u16* __restrict__ wqb, u16* __restrict__ wkb,
    u16* __restrict__ wvb, u16* __restrict__ wob)
{
    int flat = blockIdx.x;
    const float* x; u16* y; int off;
    if (flat < 8192) {
        x = flat < 4096 ? q : v;
        y = flat < 4096 ? qb : vb;
        off = flat & 4095;
    } else {
        int s = (flat - 8192) >> 9;
        off = (flat - 8192) & 511;
        x = s == 0 ? wq : (s == 1 ? wk : (s == 2 ? wv : wo));
        y = s == 0 ? wqb : (s == 1 ? wkb : (s == 2 ? wvb : wob));
    }
    int i = (off * 256 + threadIdx.x) * 8;
    float4 a = *(const float4*)(x + i);
    float4 b = *(const float4*)(x + i + 4);
    u16 o[8] = { f2b(a.x), f2b(a.y), f2b(a.z), f2b(a.w),
                 f2b(b.x), f2b(b.y), f2b(b.z), f2b(b.w) };
    *(uint4*)(y + i) = *(uint4*)o;
}

// Fused Q/K/V projections, BM=256 x BN=128, BK=32 (m97-style 2-barrier loop).
// BM=256 halves W staging traffic vs BM=128 (R4: L2/L3-BW-bound on staging).
// acc[8][4]=128 VGPR -> ~190 live, 2 waves/SIMD; launch_bounds(256,2) allows
// 256 VGPR (no spill). Grid 768 = 8 xcd x 4 m x 24 y (XCD-clustered).
// sel==2 (V) writes its output DIRECTLY TRANSPOSED into VT[(b*1024+d)*2048+l].
__global__ __launch_bounds__(256, 2) void gemm_proj(
    const u16* __restrict__ qb, const u16* __restrict__ vb,
    const u16* __restrict__ wqb, const u16* __restrict__ wkb,
    const u16* __restrict__ wvb,
    const float* __restrict__ bq, const float* __restrict__ bk,
    const float* __restrict__ bv,
    u16* __restrict__ Qp, u16* __restrict__ Kp, u16* __restrict__ VT,
    int M, int K)
{
    const int flat = blockIdx.x;
    const int xcd = flat & 7, idx = flat >> 3;     // idx in 0..95
    const int mt  = xcd * 4 + (idx & 3);           // m-tile 0..31 (256 rows each)
    const int yy  = idx >> 2;                      // 0..23
    const int sel = yy >> 3;
    const int n0 = (yy & 7) * 128;
    const u16* A = sel ? vb : qb;
    const u16* W = sel == 0 ? wqb : (sel == 1 ? wkb : wvb);
    const float* bias = sel == 0 ? bq : (sel == 1 ? bk : bv);
    const float cscale = sel == 0 ? QSCALE : 1.0f;

    __shared__ __align__(16) u16 As[256 * 32];     // 16 KB
    __shared__ __align__(16) u16 Bs[128 * 32];     //  8 KB

    const int tid  = threadIdx.x;
    const int wave = tid >> 6, lane = tid & 63;
    const int quad = lane >> 4, l16 = lane & 15;
    const int m0 = mt * 256;
    const int wm = (wave >> 1) * 128, wn = (wave & 1) * 64;
    const int r0 = lane >> 2;
    const int c0 = (lane & 3) * 8;

    f32x4 acc[8][4] = {};

    for (int k0 = 0; k0 < K; k0 += 32) {
        __syncthreads();
        {
            int ra = wave * 16 + r0;
#pragma unroll
            for (int s = 0; s < 4; ++s)
                glds16(&A[(size_t)(m0 + s * 64 + ra) * K + k0 + c0],
                       &As[(s * 64 + ra) * 32 + c0]);
#pragma unroll
            for (int s = 0; s < 2; ++s)
                glds16(&W[(size_t)(n0 + s * 64 + ra) * K + k0 + c0],
                       &Bs[(s * 64 + ra) * 32 + c0]);
        }
        __syncthreads();

        bf16x8 af[8], bfr[4];
#pragma unroll
        for (int mi = 0; mi < 8; ++mi)
            af[mi] = *(const bf16x8*)(&As[(wm + mi * 16 + l16) * 32 + quad * 8]);
#pragma unroll
        for (int ni = 0; ni < 4; ++ni)
            bfr[ni] = *(const bf16x8*)(&Bs[(wn + ni * 16 + l16) * 32 + quad * 8]);
#pragma unroll
        for (int mi = 0; mi < 8; ++mi)
#pragma unroll
            for (int ni = 0; ni < 4; ++ni)
                acc[mi][ni] = MFMA16(af[mi], bfr[ni], acc[mi][ni]);
    }

    if (sel == 2) {
        // transposed V epilogue: VT[(b*1024+col)*2048 + l], l = row & 2047
#pragma unroll
        for (int mi = 0; mi < 8; ++mi) {
#pragma unroll
            for (int ni = 0; ni < 4; ++ni) {
                int col = n0 + wn + ni * 16 + l16;
                float bv2 = bias[col];
                int row0 = m0 + wm + mi * 16 + quad * 4;   // + r, r=0..3
                int bb = row0 >> 11, l0 = row0 & 2047;
                u16 o[4];
#pragma unroll
                for (int r = 0; r < 4; ++r) o[r] = f2b(acc[mi][ni][r] + bv2);
                *(uint2*)(&VT[((size_t)bb * 1024 + col) * 2048 + l0]) = *(uint2*)o;
            }
        }
    } else {
        u16* C = sel == 0 ? Qp : Kp;
#pragma unroll
        for (int mi = 0; mi < 8; ++mi) {
#pragma unroll
            for (int ni = 0; ni < 4; ++ni) {
                int col = n0 + wn + ni * 16 + l16;
                float bv2 = bias[col];
#pragma unroll
                for (int r = 0; r < 4; ++r) {
                    int row = m0 + wm + mi * 16 + quad * 4 + r;
                    C[(size_t)row * 1024 + col] = f2b((acc[mi][ni][r] + bv2) * cscale);
                }
            }
        }
    }
}

// Output GEMM: C[M,N](fp32) = A[M,K](bf16) @ B[N,K]^T(bf16) + bias.
// m97 structure; XCD-clustered 1D grid (512 = 8 xcd x 8 m x 8 n).
__global__ __launch_bounds__(256) void gemm_out(
    const u16* __restrict__ A, const u16* __restrict__ B,
    const float* __restrict__ bias, float* __restrict__ C,
    int M, int N, int K)
{
    __shared__ __align__(16) u16 As[128 * 32];
    __shared__ __align__(16) u16 Bs[128 * 32];

    const int flat = blockIdx.x;
    const int xcd = flat & 7, idx = flat >> 3;     // idx 0..63
    const int mt  = xcd * 8 + (idx & 7);
    const int m0 = mt * 128, n0 = (idx >> 3) * 128;

    const int tid  = threadIdx.x;
    const int wave = tid >> 6, lane = tid & 63;
    const int quad = lane >> 4, l16 = lane & 15;
    const int wm = (wave >> 1) * 64, wn = (wave & 1) * 64;
    const int r0 = lane >> 2;
    const int c0 = (lane & 3) * 8;

    f32x4 acc[4][4] = {};

    for (int k0 = 0; k0 < K; k0 += 32) {
        __syncthreads();
        {
            int ra = wave * 16 + r0;
            glds16(&A[(size_t)(m0 + ra) * K + k0 + c0],      &As[ra * 32 + c0]);
            glds16(&A[(size_t)(m0 + 64 + ra) * K + k0 + c0], &As[(64 + ra) * 32 + c0]);
            glds16(&B[(size_t)(n0 + ra) * K + k0 + c0],      &Bs[ra * 32 + c0]);
            glds16(&B[(size_t)(n0 + 64 + ra) * K + k0 + c0], &Bs[(64 + ra) * 32 + c0]);
        }
        __syncthreads();

        bf16x8 af[4], bfr[4];
#pragma unroll
        for (int mi = 0; mi < 4; ++mi)
            af[mi] = *(const bf16x8*)(&As[(wm + mi * 16 + l16) * 32 + quad * 8]);
#pragma unroll
        for (int ni = 0; ni < 4; ++ni)
            bfr[ni] = *(const bf16x8*)(&Bs[(wn + ni * 16 + l16) * 32 + quad * 8]);
#pragma unroll
        for (int mi = 0; mi < 4; ++mi)
#pragma unroll
            for (int ni = 0; ni < 4; ++ni)
                acc[mi][ni] = MFMA16(af[mi], bfr[ni], acc[mi][ni]);
    }

#pragma unroll
    for (int mi = 0; mi < 4; ++mi) {
#pragma unroll
        for (int ni = 0; ni < 4; ++ni) {
            int col = n0 + wn + ni * 16 + l16;
            float bv = bias[col];
#pragma unroll
            for (int r = 0; r < 4; ++r) {
                int row = m0 + wm + mi * 16 + quad * 4 + r;
                C[(size_t)row * N + col] = acc[mi][ni][r] + bv;
            }
        }
    }
}

// Flash attention, 2 waves x 64 q-rows. R7 post-mortem: V must stay staged
// in LDS (V-direct-from-L2 regressed 89.7->102 us: vmcnt stall before every
// PV phase + duplicated per-wave L2 traffic). This round: K/V staging via
// global_load_lds (async, no VGPR round-trip, removes 8 ds_write + 8 global
// load instrs per wave-iter = ~20% of DS-pipe cycles). Rule #21 pattern:
// LINEAR LDS dest (rows of 64 u16, no padding) + XOR-swizzled GLOBAL source
// col ^= (row&7)<<3 + same XOR on the LDS read side. Bank math: kf/vf b128
// reads land 8 lanes per 4-bank group (same balance as the old padded-72
// layout, conflict-free); staging coalescing unchanged (XOR permutes 16B
// blocks within each 128B row).
// Q pre-scaled by 0.125*log2e so p = exp2(S), max-free. S computed
// TRANSPOSED (mfma(kf,qf)); pack 4 truncated bf16 -> one ds_write_b64;
// denominator via vones MFMA = exactly consistent with truncated P.
// NOTE (R2): reg-staging next K/V tile spills. NOTE (R4): VALU rowsum
// costs more than the 4 MFMA it saves.
__global__ __launch_bounds__(128, 2) void attn(
    const u16* __restrict__ Q, const u16* __restrict__ K,
    const u16* __restrict__ VT, u16* __restrict__ O,
    int LQ, int LK)
{
    const int tid  = threadIdx.x;
    const int wave = tid >> 6, lane = tid & 63;
    const int quad = lane >> 4, l16 = lane & 15;
    // XCD-clustered decode (bijective, 8 xcd x 8 bh x 16 q-blocks = 1024):
    const int flat = blockIdx.x;
    const int xcd = flat & 7, slot = flat >> 3;
    const int bh = xcd * 8 + (slot >> 4);
    const int q0 = (slot & 15) * 128;
    const int b = bh >> 4, h = bh & 15;
    const size_t qbase = ((size_t)b * LQ + q0) * 1024 + h * 64;
    const size_t kbase = ((size_t)b * LK) * 1024 + h * 64;
    const size_t vtbase = ((size_t)b * 1024 + h * 64) * 2048;

    __shared__ __align__(16) u16 Ks[64 * 64];        // [krow][d^swz]  8 KB
    __shared__ __align__(16) u16 VTs[64 * 64];       // [d][krow^swz]  8 KB
    __shared__ __align__(16) u16 Ps[2][64 * 40];     // per-wave P    10 KB

    bf16x8 qf[4][2];
#pragma unroll
    for (int mi = 0; mi < 4; ++mi)
#pragma unroll
        for (int ks = 0; ks < 2; ++ks)
            qf[mi][ks] = *(const bf16x8*)(
                &Q[qbase + (size_t)(wave * 64 + mi * 16 + l16) * 1024 + ks * 32 + quad * 8]);

    const bf16x8 vones = { 0x3F80, 0x3F80, 0x3F80, 0x3F80,
                           0x3F80, 0x3F80, 0x3F80, 0x3F80 };

    f32x4 oacc[4][5] = {};   // [q-tile][4 d-tiles + 1 rowsum tile]

    const int swzr = (l16 & 7) << 3;   // read-side XOR (elements)

    for (int kt = 0; kt < LK; kt += 64) {
        __syncthreads();               // WAR: prior iter's LDS reads done
#pragma unroll
        for (int i = 0; i < 4; ++i) {
            int ch = tid + i * 128;
            int row = ch >> 3;
            int csw = ((ch & 7) * 8) ^ ((row & 7) << 3);   // swizzled source col
            glds16(&K[kbase + (size_t)(kt + row) * 1024 + csw], &Ks[ch * 8]);
            glds16(&VT[vtbase + (size_t)row * 2048 + kt + csw], &VTs[ch * 8]);
        }
        __syncthreads();               // tiles published (vmcnt drained here)

        // S^T tiles: st[ni][mi] = K-tile(ni) x Q-tile(mi); lane (quad,l16) reg r
        // holds S[q = mi*16+l16][k = ni*16+quad*4+r]
        f32x4 st[4][4] = {};
#pragma unroll
        for (int ks = 0; ks < 2; ++ks) {
            bf16x8 kf[4];
#pragma unroll
            for (int ni = 0; ni < 4; ++ni)
                kf[ni] = *(const bf16x8*)(
                    &Ks[(ni * 16 + l16) * 64 + (((ks * 32) + quad * 8) ^ swzr)]);
            __builtin_amdgcn_s_setprio(1);
#pragma unroll
            for (int ni = 0; ni < 4; ++ni)
#pragma unroll
                for (int mi = 0; mi < 4; ++mi)
                    st[ni][mi] = MFMA16(kf[ni], qf[mi][ks], st[ni][mi]);
            __builtin_amdgcn_s_setprio(0);
        }

        // per 32-col ks-slice: p = exp2(s), pack -> Ps slice, then PV MFMA.
        // Ps is wave-private; same-wave in-order DS ops give RAW/WAR ordering.
#pragma unroll
        for (int ks = 0; ks < 2; ++ks) {
#pragma unroll
            for (int mi = 0; mi < 4; ++mi)
#pragma unroll
                for (int ni2 = 0; ni2 < 2; ++ni2) {
                    const f32x4 s4 = st[ks * 2 + ni2][mi];
                    float p0 = __builtin_amdgcn_exp2f(s4[0]);
                    float p1 = __builtin_amdgcn_exp2f(s4[1]);
                    float p2 = __builtin_amdgcn_exp2f(s4[2]);
                    float p3 = __builtin_amdgcn_exp2f(s4[3]);
                    uint2 w;
                    w.x = pack2_trunc(p0, p1);
                    w.y = pack2_trunc(p2, p3);
                    *(uint2*)(&Ps[wave][(mi * 16 + l16) * 40 + ni2 * 16 + quad * 4]) = w;
                }

            bf16x8 vf[4];
#pragma unroll
            for (int nd = 0; nd < 4; ++nd)
                vf[nd] = *(const bf16x8*)(
                    &VTs[(nd * 16 + l16) * 64 + (((ks * 32) + quad * 8) ^ swzr)]);
            __builtin_amdgcn_s_setprio(1);
#pragma unroll
            for (int mi = 0; mi < 4; ++mi) {
                bf16x8 pf = *(const bf16x8*)(&Ps[wave][(mi * 16 + l16) * 40 + quad * 8]);
#pragma unroll
                for (int nd = 0; nd < 4; ++nd)
                    oacc[mi][nd] = MFMA16(pf, vf[nd], oacc[mi][nd]);
                oacc[mi][4] = MFMA16(pf, vones, oacc[mi][4]);
            }
            __builtin_amdgcn_s_setprio(0);
        }
    }

    // epilogue: divide by MFMA-computed row sums, store
#pragma unroll
    for (int mi = 0; mi < 4; ++mi)
#pragma unroll
        for (int r = 0; r < 4; ++r) {
            float inv = 1.0f / oacc[mi][4][r];
            int row = q0 + wave * 64 + mi * 16 + quad * 4 + r;
            size_t rb = ((size_t)b * LQ + row) * 1024 + h * 64;
#pragma unroll
            for (int nd = 0; nd < 4; ++nd)
                O[rb + nd * 16 + l16] = f2b(oacc[mi][nd][r] * inv);
        }
}

extern "C" void kernel_launch(void* const* d_in, const int* in_sizes, int n_in,
                              void* d_out, int out_size, void* d_ws, size_t ws_size,
                              hipStream_t stream) {
    const float* query = (const float*)d_in[0];
    const float* value = (const float*)d_in[1];
    const float* wq = (const float*)d_in[2];
    const float* bq = (const float*)d_in[3];
    const float* wk = (const float*)d_in[4];
    const float* bk = (const float*)d_in[5];
    const float* wv = (const float*)d_in[6];
    const float* bv = (const float*)d_in[7];
    const float* wo = (const float*)d_in[8];
    const float* bo = (const float*)d_in[9];

    const int B = 4, LQ = 2048, LK = 2048, D = 1024;
    const int M = B * LQ;                 // 8192
    const int mat = M * D;                // 8388608
    const int wsz = D * D;                // 1048576

    // ws (u16): qb vb | wqb wkb wvb wob | Qp Kp Cp VT  = 104 MB
    u16* ws  = (u16*)d_ws;
    u16* qb  = ws;
    u16* vb  = qb + mat;
    u16* wqb = vb + mat;
    u16* wkb = wqb + wsz;
    u16* wvb = wkb + wsz;
    u16* wob = wvb + wsz;
    u16* Qp  = wob + wsz;
    u16* Kp  = Qp + mat;
    u16* Cp  = Kp + mat;                  // attn output
    u16* VT  = Cp + mat;                  // V projection, stored transposed

    dim3 blk(256);

    cvt_all<<<dim3(10240), blk, 0, stream>>>(
        query, value, wq, wk, wv, wo, qb, vb, wqb, wkb, wvb, wob);

    // fused Q/K/V projections: BM=256, XCD-clustered flat grid (768 blocks);
    // V written directly transposed into VT.
    gemm_proj<<<dim3(768), blk, 0, stream>>>(
        qb, vb, wqb, wkb, wvb, bq, bk, bv, Qp, Kp, VT, M, D);

    attn<<<dim3(1024), dim3(128), 0, stream>>>(Qp, Kp, VT, Cp, LQ, LK);

    gemm_out<<<dim3(512), blk, 0, stream>>>(Cp, wob, bo, (float*)d_out, M, D, D);
}

// Round 9
// 299.086 us; speedup vs baseline: 1.0776x; 1.0568x over previous
//
#include <hip/hip_runtime.h>
#include <hip/hip_bf16.h>

typedef unsigned short u16;
typedef unsigned int u32;
typedef __attribute__((ext_vector_type(8))) short bf16x8;
typedef __attribute__((ext_vector_type(4))) float f32x4;

#define MFMA16(a, b, c) __builtin_amdgcn_mfma_f32_16x16x32_bf16(a, b, c, 0, 0, 0)

// fold of softmax scale into Q projection: exp(s/8) = 2^(s*0.125*log2(e))
#define QSCALE 0.18033688011112042f

__device__ inline u16 f2b(float f) {
    union { float f; unsigned int i; } v;
    v.f = f;
    unsigned int r = v.i + 0x7fffu + ((v.i >> 16) & 1u);
    return (u16)(r >> 16);
}
__device__ inline u32 fbits(float f) {
    union { float f; u32 i; } v; v.f = f; return v.i;
}
// pack two fp32 -> [bf16(f0) | bf16(f1)<<16], truncation, 1 v_perm_b32
__device__ inline u32 pack2_trunc(float f0, float f1) {
    return __builtin_amdgcn_perm(fbits(f1), fbits(f0), 0x07060302u);
}

// async global->LDS, 16B per lane (wave-uniform base + lane*16 dest).
__device__ inline void glds16(const u16* g, u16* l) {
    __builtin_amdgcn_global_load_lds(
        (const __attribute__((address_space(1))) unsigned int*)g,
        (__attribute__((address_space(3))) unsigned int*)l, 16, 0, 0);
}

// All six fp32->bf16 conversions in ONE dispatch, flat 1D decode.
// chunks: query 4096 | value 4096 | wq/wk/wv/wo 512 each  (total 10240)
__global__ __launch_bounds__(256) void cvt_all(
    const float* __restrict__ q, const float* __restrict__ v,
    const float* __restrict__ wq, const float* __restrict__ wk,
    const float* __restrict__ wv, const float* __restrict__ wo,
    u16* __restrict__ qb, u16* __restrict__ vb,
    u16* __restrict__ wqb, u16* __restrict__ wkb,
    u16* __restrict__ wvb, u16* __restrict__ wob)
{
    int flat = blockIdx.x;
    const float* x; u16* y; int off;
    if (flat < 8192) {
        x = flat < 4096 ? q : v;
        y = flat < 4096 ? qb : vb;
        off = flat & 4095;
    } else {
        int s = (flat - 8192) >> 9;
        off = (flat - 8192) & 511;
        x = s == 0 ? wq : (s == 1 ? wk : (s == 2 ? wv : wo));
        y = s == 0 ? wqb : (s == 1 ? wkb : (s == 2 ? wvb : wob));
    }
    int i = (off * 256 + threadIdx.x) * 8;
    float4 a = *(const float4*)(x + i);
    float4 b = *(const float4*)(x + i + 4);
    u16 o[8] = { f2b(a.x), f2b(a.y), f2b(a.z), f2b(a.w),
                 f2b(b.x), f2b(b.y), f2b(b.z), f2b(b.w) };
    *(uint4*)(y + i) = *(uint4*)o;
}

// Fused Q/K/V projections, BM=256 x BN=128, BK=64 (2-barrier loop).
// R8 analysis: proj is NOT pure staging-BW-bound (BM 128->256 cut traffic
// 24% but time only 8%) -> the barrier/vmcnt-drain fixed cost dominates.
// BK=64 halves barrier count, doubles MFMA-per-barrier. 128B LDS rows use
// the R8-proven rule-#21 swizzle: linear LDS dest (global_load_lds) +
// XOR-swizzled GLOBAL source chunk (c ^= row&7, 16B units) + same XOR on
// the b128 read -> 8 lanes/4-bank group (1KB/wave minimum, conflict-free),
// coalescing preserved (XOR permutes 16B blocks within each 128B row).
// LDS 48 KB, 2 blocks/CU; ~190 VGPR live, launch_bounds(256,2) (no spill).
// Grid 768 = 8 xcd x 4 m x 24 y. sel==2 (V) writes DIRECTLY TRANSPOSED
// into VT[(b*1024+d)*2048+l].
__global__ __launch_bounds__(256, 2) void gemm_proj(
    const u16* __restrict__ qb, const u16* __restrict__ vb,
    const u16* __restrict__ wqb, const u16* __restrict__ wkb,
    const u16* __restrict__ wvb,
    const float* __restrict__ bq, const float* __restrict__ bk,
    const float* __restrict__ bv,
    u16* __restrict__ Qp, u16* __restrict__ Kp, u16* __restrict__ VT,
    int M, int K)
{
    const int flat = blockIdx.x;
    const int xcd = flat & 7, idx = flat >> 3;     // idx in 0..95
    const int mt  = xcd * 4 + (idx & 3);           // m-tile 0..31 (256 rows each)
    const int yy  = idx >> 2;                      // 0..23
    const int sel = yy >> 3;
    const int n0 = (yy & 7) * 128;
    const u16* A = sel ? vb : qb;
    const u16* W = sel == 0 ? wqb : (sel == 1 ? wkb : wvb);
    const float* bias = sel == 0 ? bq : (sel == 1 ? bk : bv);
    const float cscale = sel == 0 ? QSCALE : 1.0f;

    __shared__ __align__(16) u16 As[256 * 64];     // 32 KB, swizzled chunks
    __shared__ __align__(16) u16 Bs[128 * 64];     // 16 KB, swizzled chunks

    const int tid  = threadIdx.x;
    const int wave = tid >> 6, lane = tid & 63;
    const int quad = lane >> 4, l16 = lane & 15;
    const int m0 = mt * 256;
    const int wm = (wave >> 1) * 128, wn = (wave & 1) * 64;

    f32x4 acc[8][4] = {};

    for (int k0 = 0; k0 < K; k0 += 64) {
        __syncthreads();
        // A tile: 2048 chunks (16B each), i = 0..7
#pragma unroll
        for (int i = 0; i < 8; ++i) {
            int ch = tid + i * 256;
            int row = ch >> 3, c = ch & 7;
            glds16(&A[(size_t)(m0 + row) * K + k0 + ((c ^ (row & 7)) * 8)],
                   &As[ch * 8]);
        }
        // B tile: 1024 chunks, i = 0..3
#pragma unroll
        for (int i = 0; i < 4; ++i) {
            int ch = tid + i * 256;
            int row = ch >> 3, c = ch & 7;
            glds16(&W[(size_t)(n0 + row) * K + k0 + ((c ^ (row & 7)) * 8)],
                   &Bs[ch * 8]);
        }
        __syncthreads();

#pragma unroll
        for (int ks = 0; ks < 2; ++ks) {
            bf16x8 af[8], bfr[4];
#pragma unroll
            for (int mi = 0; mi < 8; ++mi) {
                int row = wm + mi * 16 + l16;
                af[mi] = *(const bf16x8*)(
                    &As[row * 64 + (((ks * 4 + quad) ^ (row & 7)) * 8)]);
            }
#pragma unroll
            for (int ni = 0; ni < 4; ++ni) {
                int row = wn + ni * 16 + l16;
                bfr[ni] = *(const bf16x8*)(
                    &Bs[row * 64 + (((ks * 4 + quad) ^ (row & 7)) * 8)]);
            }
#pragma unroll
            for (int mi = 0; mi < 8; ++mi)
#pragma unroll
                for (int ni = 0; ni < 4; ++ni)
                    acc[mi][ni] = MFMA16(af[mi], bfr[ni], acc[mi][ni]);
        }
    }

    if (sel == 2) {
        // transposed V epilogue: VT[(b*1024+col)*2048 + l], l = row & 2047
#pragma unroll
        for (int mi = 0; mi < 8; ++mi) {
#pragma unroll
            for (int ni = 0; ni < 4; ++ni) {
                int col = n0 + wn + ni * 16 + l16;
                float bv2 = bias[col];
                int row0 = m0 + wm + mi * 16 + quad * 4;   // + r, r=0..3
                int bb = row0 >> 11, l0 = row0 & 2047;
                u16 o[4];
#pragma unroll
                for (int r = 0; r < 4; ++r) o[r] = f2b(acc[mi][ni][r] + bv2);
                *(uint2*)(&VT[((size_t)bb * 1024 + col) * 2048 + l0]) = *(uint2*)o;
            }
        }
    } else {
        u16* C = sel == 0 ? Qp : Kp;
#pragma unroll
        for (int mi = 0; mi < 8; ++mi) {
#pragma unroll
            for (int ni = 0; ni < 4; ++ni) {
                int col = n0 + wn + ni * 16 + l16;
                float bv2 = bias[col];
#pragma unroll
                for (int r = 0; r < 4; ++r) {
                    int row = m0 + wm + mi * 16 + quad * 4 + r;
                    C[(size_t)row * 1024 + col] = f2b((acc[mi][ni][r] + bv2) * cscale);
                }
            }
        }
    }
}

// Output GEMM: C[M,N](fp32) = A[M,K](bf16) @ B[N,K]^T(bf16) + bias.
// BK=64 + rule-#21 swizzled staging (same mechanic as gemm_proj above).
// XCD-clustered 1D grid (512 = 8 xcd x 8 m x 8 n). LDS 32 KB.
__global__ __launch_bounds__(256) void gemm_out(
    const u16* __restrict__ A, const u16* __restrict__ B,
    const float* __restrict__ bias, float* __restrict__ C,
    int M, int N, int K)
{
    __shared__ __align__(16) u16 As[128 * 64];     // 16 KB
    __shared__ __align__(16) u16 Bs[128 * 64];     // 16 KB

    const int flat = blockIdx.x;
    const int xcd = flat & 7, idx = flat >> 3;     // idx 0..63
    const int mt  = xcd * 8 + (idx & 7);
    const int m0 = mt * 128, n0 = (idx >> 3) * 128;

    const int tid  = threadIdx.x;
    const int wave = tid >> 6, lane = tid & 63;
    const int quad = lane >> 4, l16 = lane & 15;
    const int wm = (wave >> 1) * 64, wn = (wave & 1) * 64;

    f32x4 acc[4][4] = {};

    for (int k0 = 0; k0 < K; k0 += 64) {
        __syncthreads();
#pragma unroll
        for (int i = 0; i < 4; ++i) {
            int ch = tid + i * 256;
            int row = ch >> 3, c = ch & 7;
            glds16(&A[(size_t)(m0 + row) * K + k0 + ((c ^ (row & 7)) * 8)],
                   &As[ch * 8]);
        }
#pragma unroll
        for (int i = 0; i < 4; ++i) {
            int ch = tid + i * 256;
            int row = ch >> 3, c = ch & 7;
            glds16(&B[(size_t)(n0 + row) * K + k0 + ((c ^ (row & 7)) * 8)],
                   &Bs[ch * 8]);
        }
        __syncthreads();

#pragma unroll
        for (int ks = 0; ks < 2; ++ks) {
            bf16x8 af[4], bfr[4];
#pragma unroll
            for (int mi = 0; mi < 4; ++mi) {
                int row = wm + mi * 16 + l16;
                af[mi] = *(const bf16x8*)(
                    &As[row * 64 + (((ks * 4 + quad) ^ (row & 7)) * 8)]);
            }
#pragma unroll
            for (int ni = 0; ni < 4; ++ni) {
                int row = wn + ni * 16 + l16;
                bfr[ni] = *(const bf16x8*)(
                    &Bs[row * 64 + (((ks * 4 + quad) ^ (row & 7)) * 8)]);
            }
#pragma unroll
            for (int mi = 0; mi < 4; ++mi)
#pragma unroll
                for (int ni = 0; ni < 4; ++ni)
                    acc[mi][ni] = MFMA16(af[mi], bfr[ni], acc[mi][ni]);
        }
    }

#pragma unroll
    for (int mi = 0; mi < 4; ++mi) {
#pragma unroll
        for (int ni = 0; ni < 4; ++ni) {
            int col = n0 + wn + ni * 16 + l16;
            float bv = bias[col];
#pragma unroll
            for (int r = 0; r < 4; ++r) {
                int row = m0 + wm + mi * 16 + quad * 4 + r;
                C[(size_t)row * N + col] = acc[mi][ni][r] + bv;
            }
        }
    }
}

// Flash attention, 2 waves x 64 q-rows, K/V staged via swizzled
// global_load_lds (R8, verified: bank conflicts 1.05e7 -> 6.3e6).
// V must stay in LDS (R7: direct-from-L2 regressed 89.7->102).
// Q pre-scaled by 0.125*log2e so p = exp2(S), max-free. S computed
// TRANSPOSED (mfma(kf,qf)); pack 4 truncated bf16 -> one ds_write_b64;
// denominator via vones MFMA = exactly consistent with truncated P.
// NOTE (R2): reg-staging next K/V tile spills. NOTE (R4): VALU rowsum
// costs more than the 4 MFMA it saves.
__global__ __launch_bounds__(128, 2) void attn(
    const u16* __restrict__ Q, const u16* __restrict__ K,
    const u16* __restrict__ VT, u16* __restrict__ O,
    int LQ, int LK)
{
    const int tid  = threadIdx.x;
    const int wave = tid >> 6, lane = tid & 63;
    const int quad = lane >> 4, l16 = lane & 15;
    // XCD-clustered decode (bijective, 8 xcd x 8 bh x 16 q-blocks = 1024):
    const int flat = blockIdx.x;
    const int xcd = flat & 7, slot = flat >> 3;
    const int bh = xcd * 8 + (slot >> 4);
    const int q0 = (slot & 15) * 128;
    const int b = bh >> 4, h = bh & 15;
    const size_t qbase = ((size_t)b * LQ + q0) * 1024 + h * 64;
    const size_t kbase = ((size_t)b * LK) * 1024 + h * 64;
    const size_t vtbase = ((size_t)b * 1024 + h * 64) * 2048;

    __shared__ __align__(16) u16 Ks[64 * 64];        // [krow][d^swz]  8 KB
    __shared__ __align__(16) u16 VTs[64 * 64];       // [d][krow^swz]  8 KB
    __shared__ __align__(16) u16 Ps[2][64 * 40];     // per-wave P    10 KB

    bf16x8 qf[4][2];
#pragma unroll
    for (int mi = 0; mi < 4; ++mi)
#pragma unroll
        for (int ks = 0; ks < 2; ++ks)
            qf[mi][ks] = *(const bf16x8*)(
                &Q[qbase + (size_t)(wave * 64 + mi * 16 + l16) * 1024 + ks * 32 + quad * 8]);

    const bf16x8 vones = { 0x3F80, 0x3F80, 0x3F80, 0x3F80,
                           0x3F80, 0x3F80, 0x3F80, 0x3F80 };

    f32x4 oacc[4][5] = {};   // [q-tile][4 d-tiles + 1 rowsum tile]

    const int swzr = (l16 & 7) << 3;   // read-side XOR (elements)

    for (int kt = 0; kt < LK; kt += 64) {
        __syncthreads();               // WAR: prior iter's LDS reads done
#pragma unroll
        for (int i = 0; i < 4; ++i) {
            int ch = tid + i * 128;
            int row = ch >> 3;
            int csw = ((ch & 7) * 8) ^ ((row & 7) << 3);   // swizzled source col
            glds16(&K[kbase + (size_t)(kt + row) * 1024 + csw], &Ks[ch * 8]);
            glds16(&VT[vtbase + (size_t)row * 2048 + kt + csw], &VTs[ch * 8]);
        }
        __syncthreads();               // tiles published (vmcnt drained here)

        // S^T tiles: st[ni][mi] = K-tile(ni) x Q-tile(mi); lane (quad,l16) reg r
        // holds S[q = mi*16+l16][k = ni*16+quad*4+r]
        f32x4 st[4][4] = {};
#pragma unroll
        for (int ks = 0; ks < 2; ++ks) {
            bf16x8 kf[4];
#pragma unroll
            for (int ni = 0; ni < 4; ++ni)
                kf[ni] = *(const bf16x8*)(
                    &Ks[(ni * 16 + l16) * 64 + (((ks * 32) + quad * 8) ^ swzr)]);
            __builtin_amdgcn_s_setprio(1);
#pragma unroll
            for (int ni = 0; ni < 4; ++ni)
#pragma unroll
                for (int mi = 0; mi < 4; ++mi)
                    st[ni][mi] = MFMA16(kf[ni], qf[mi][ks], st[ni][mi]);
            __builtin_amdgcn_s_setprio(0);
        }

        // per 32-col ks-slice: p = exp2(s), pack -> Ps slice, then PV MFMA.
        // Ps is wave-private; same-wave in-order DS ops give RAW/WAR ordering.
#pragma unroll
        for (int ks = 0; ks < 2; ++ks) {
#pragma unroll
            for (int mi = 0; mi < 4; ++mi)
#pragma unroll
                for (int ni2 = 0; ni2 < 2; ++ni2) {
                    const f32x4 s4 = st[ks * 2 + ni2][mi];
                    float p0 = __builtin_amdgcn_exp2f(s4[0]);
                    float p1 = __builtin_amdgcn_exp2f(s4[1]);
                    float p2 = __builtin_amdgcn_exp2f(s4[2]);
                    float p3 = __builtin_amdgcn_exp2f(s4[3]);
                    uint2 w;
                    w.x = pack2_trunc(p0, p1);
                    w.y = pack2_trunc(p2, p3);
                    *(uint2*)(&Ps[wave][(mi * 16 + l16) * 40 + ni2 * 16 + quad * 4]) = w;
                }

            bf16x8 vf[4];
#pragma unroll
            for (int nd = 0; nd < 4; ++nd)
                vf[nd] = *(const bf16x8*)(
                    &VTs[(nd * 16 + l16) * 64 + (((ks * 32) + quad * 8) ^ swzr)]);
            __builtin_amdgcn_s_setprio(1);
#pragma unroll
            for (int mi = 0; mi < 4; ++mi) {
                bf16x8 pf = *(const bf16x8*)(&Ps[wave][(mi * 16 + l16) * 40 + quad * 8]);
#pragma unroll
                for (int nd = 0; nd < 4; ++nd)
                    oacc[mi][nd] = MFMA16(pf, vf[nd], oacc[mi][nd]);
                oacc[mi][4] = MFMA16(pf, vones, oacc[mi][4]);
            }
            __builtin_amdgcn_s_setprio(0);
        }
    }

    // epilogue: divide by MFMA-computed row sums, store
#pragma unroll
    for (int mi = 0; mi < 4; ++mi)
#pragma unroll
        for (int r = 0; r < 4; ++r) {
            float inv = 1.0f / oacc[mi][4][r];
            int row = q0 + wave * 64 + mi * 16 + quad * 4 + r;
            size_t rb = ((size_t)b * LQ + row) * 1024 + h * 64;
#pragma unroll
            for (int nd = 0; nd < 4; ++nd)
                O[rb + nd * 16 + l16] = f2b(oacc[mi][nd][r] * inv);
        }
}

extern "C" void kernel_launch(void* const* d_in, const int* in_sizes, int n_in,
                              void* d_out, int out_size, void* d_ws, size_t ws_size,
                              hipStream_t stream) {
    const float* query = (const float*)d_in[0];
    const float* value = (const float*)d_in[1];
    const float* wq = (const float*)d_in[2];
    const float* bq = (const float*)d_in[3];
    const float* wk = (const float*)d_in[4];
    const float* bk = (const float*)d_in[5];
    const float* wv = (const float*)d_in[6];
    const float* bv = (const float*)d_in[7];
    const float* wo = (const float*)d_in[8];
    const float* bo = (const float*)d_in[9];

    const int B = 4, LQ = 2048, LK = 2048, D = 1024;
    const int M = B * LQ;                 // 8192
    const int mat = M * D;                // 8388608
    const int wsz = D * D;                // 1048576

    // ws (u16): qb vb | wqb wkb wvb wob | Qp Kp Cp VT  = 104 MB
    u16* ws  = (u16*)d_ws;
    u16* qb  = ws;
    u16* vb  = qb + mat;
    u16* wqb = vb + mat;
    u16* wkb = wqb + wsz;
    u16* wvb = wkb + wsz;
    u16* wob = wvb + wsz;
    u16* Qp  = wob + wsz;
    u16* Kp  = Qp + mat;
    u16* Cp  = Kp + mat;                  // attn output
    u16* VT  = Cp + mat;                  // V projection, stored transposed

    dim3 blk(256);

    cvt_all<<<dim3(10240), blk, 0, stream>>>(
        query, value, wq, wk, wv, wo, qb, vb, wqb, wkb, wvb, wob);

    // fused Q/K/V projections: BM=256 BK=64, XCD-clustered flat grid (768);
    // V written directly transposed into VT.
    gemm_proj<<<dim3(768), blk, 0, stream>>>(
        qb, vb, wqb, wkb, wvb, bq, bk, bv, Qp, Kp, VT, M, D);

    attn<<<dim3(1024), dim3(128), 0, stream>>>(Qp, Kp, VT, Cp, LQ, LK);

    gemm_out<<<dim3(512), blk, 0, stream>>>(Cp, wob, bo, (float*)d_out, M, D, D);
}